// Round 1
// baseline (189.704 us; speedup 1.0000x reference)
//
#include <hip/hip_runtime.h>

typedef unsigned short u16;
typedef __attribute__((ext_vector_type(8))) short bf16x8;
typedef __attribute__((ext_vector_type(4))) float f32x4;

#define MFMA(a, b, c) __builtin_amdgcn_mfma_f32_16x16x32_bf16(a, b, c, 0, 0, 0)

// global -> LDS direct copy, 16 B per lane. LDS dest must be wave-uniform base
// (HW adds lane*16). Global source is per-lane.
#define GLDS16(gp, lp)                                                        \
  __builtin_amdgcn_global_load_lds(                                          \
      (__attribute__((address_space(1))) void*)(void*)(gp),                  \
      (__attribute__((address_space(3))) void*)(lp), 16, 0, 0)

__device__ __forceinline__ u16 f2b(float f) {
  union { float f; unsigned u; } x; x.f = f;
  unsigned r = x.u + 0x7fffu + ((x.u >> 16) & 1u);
  return (u16)(r >> 16);
}

// Stage a [32*NPASS rows][64 cols] bf16 tile into LDS (linear [row][64] layout)
// with XOR-swizzled SOURCE slots so that a swizzled ds_read recovers linear data.
// src points at tile origin; ld = row stride in elements.
template <int NPASS>
__device__ __forceinline__ void stage64(const u16* __restrict__ src, int ld,
                                        u16* lds, int t) {
  int wave = t >> 6;
#pragma unroll
  for (int p = 0; p < NPASS; ++p) {
    int row = p * 32 + (t >> 3);
    int ss = (t & 7) ^ (row & 7);
    const u16* g = src + row * ld + ss * 8;
    GLDS16(g, lds + (p * 2048 + wave * 512));
  }
}

// read one MFMA fragment (8 consecutive bf16) at [row][slot*8], swizzle-corrected
__device__ __forceinline__ bf16x8 ldsfrag(const u16* base, int row, int slot) {
  int byte = row * 128 + (((slot) ^ (row & 7)) << 4);
  return *(const bf16x8*)((const char*)base + byte);
}

// ---------------------------------------------------------------- prep kernels
__global__ void cast_x_kernel(const float* __restrict__ in, u16* __restrict__ out,
                              int n4) {
  int i = blockIdx.x * blockDim.x + threadIdx.x;
  if (i < n4) {
    float4 v = ((const float4*)in)[i];
    ushort4 o;
    o.x = f2b(v.x); o.y = f2b(v.y); o.z = f2b(v.z); o.w = f2b(v.w);
    ((ushort4*)out)[i] = o;
  }
}

// out[(c, r)] = bf16(in[(r, c)]); in is (R, Ccols) fp32 row-major.
__global__ void transpose_cast(const float* __restrict__ in, u16* __restrict__ out,
                               int R, int Ccols) {
  __shared__ u16 tile[32][33];
  int c0 = blockIdx.x * 32, r0 = blockIdx.y * 32;
  int tx = threadIdx.x & 31, ty = threadIdx.x >> 5;
#pragma unroll
  for (int rr = ty; rr < 32; rr += 8)
    tile[rr][tx] = f2b(in[(size_t)(r0 + rr) * Ccols + c0 + tx]);
  __syncthreads();
#pragma unroll
  for (int rr = ty; rr < 32; rr += 8)
    out[(size_t)(c0 + rr) * R + r0 + tx] = tile[tx][rr];
}

// ---------------------------------------------------------------- GEMM 128x128
// C = A(M,K) @ BT(N,K)^T, bf16 inputs, fp32 accum.
// EPI==0: scatter into q (scaled 0.125), k [(b,h,n,d)] and vT [(b,h,d,n)] bf16.
// EPI==1: out[row*Nld+col] = val + pb[col] (fp32).
template <int EPI>
__global__ __launch_bounds__(256, 2) void gemm128(
    const u16* __restrict__ A, const u16* __restrict__ BT, int K,
    u16* __restrict__ qo, u16* __restrict__ ko, u16* __restrict__ vo,
    const float* __restrict__ pb, float* __restrict__ out, int Nld) {
  __shared__ __align__(16) u16 As[128 * 64];
  __shared__ __align__(16) u16 Bs[128 * 64];
  const int t = threadIdx.x;
  const int wave = t >> 6, lane = t & 63;
  const int wr = wave >> 1, wc = wave & 1;
  const int tileRow = blockIdx.y * 128, tileCol = blockIdx.x * 128;
  const u16* Ab = A + (size_t)tileRow * K;
  const u16* Bb = BT + (size_t)tileCol * K;

  f32x4 acc[4][4] = {};
  for (int k0 = 0; k0 < K; k0 += 64) {
    __syncthreads();
    stage64<4>(Ab + k0, K, As, t);
    stage64<4>(Bb + k0, K, Bs, t);
    __syncthreads();
#pragma unroll
    for (int kk = 0; kk < 2; ++kk) {
      bf16x8 af[4], bfr[4];
#pragma unroll
      for (int m = 0; m < 4; ++m)
        af[m] = ldsfrag(As, wr * 64 + m * 16 + (lane & 15), kk * 4 + (lane >> 4));
#pragma unroll
      for (int n = 0; n < 4; ++n)
        bfr[n] = ldsfrag(Bs, wc * 64 + n * 16 + (lane & 15), kk * 4 + (lane >> 4));
#pragma unroll
      for (int m = 0; m < 4; ++m)
#pragma unroll
        for (int n = 0; n < 4; ++n)
          acc[m][n] = MFMA(af[m], bfr[n], acc[m][n]);
    }
  }

#pragma unroll
  for (int m = 0; m < 4; ++m) {
#pragma unroll
    for (int n = 0; n < 4; ++n) {
#pragma unroll
      for (int r = 0; r < 4; ++r) {
        int row = tileRow + wr * 64 + m * 16 + (lane >> 4) * 4 + r;
        int col = tileCol + wc * 64 + n * 16 + (lane & 15);
        float val = acc[m][n][r];
        if (EPI == 0) {
          int which = col / 768;
          int c = col - which * 768;
          int hh = c >> 6, d = c & 63;
          int bb = row >> 10, nn = row & 1023;
          size_t bhnd = ((size_t)(bb * 12 + hh) * 1024 + nn) * 64 + d;
          if (which == 0)
            qo[bhnd] = f2b(val * 0.125f);
          else if (which == 1)
            ko[bhnd] = f2b(val);
          else
            vo[((size_t)(bb * 12 + hh) * 64 + d) * 1024 + nn] = f2b(val);
        } else {
          out[(size_t)row * Nld + col] = val + pb[col];
        }
      }
    }
  }
}

// ---------------------------------------------------------------- attention
// grid: (qtile=16, head=12, batch=8); block: 256 (4 waves x 16 q-rows).
__global__ __launch_bounds__(256, 2) void attn_kernel(
    const u16* __restrict__ q, const u16* __restrict__ kmat,
    const u16* __restrict__ vT, const float* __restrict__ btab,
    u16* __restrict__ ao) {
  __shared__ float bias_s[3969];
  __shared__ __align__(16) u16 Ks[64 * 64];
  __shared__ __align__(16) u16 Vs[64 * 64];
  __shared__ __align__(16) u16 Ps[64 * 64];

  const int t = threadIdx.x;
  const int wave = t >> 6, lane = t & 63;
  const int qt = blockIdx.x, h = blockIdx.y, b = blockIdx.z;
  const int bh = b * 12 + h;

  // stage this head's reachable bias slice (63*63) into LDS
  for (int r = t; r < 3969; r += 256) bias_s[r] = btab[r * 12 + h];

  // Q fragments held in registers for the whole block (q pre-scaled by 0.125)
  const u16* qb = q + ((size_t)bh * 1024 + qt * 64) * 64;
  const int qrow = wave * 16 + (lane & 15);
  bf16x8 qf[2];
#pragma unroll
  for (int kk = 0; kk < 2; ++kk)
    qf[kk] = *(const bf16x8*)(qb + qrow * 64 + kk * 32 + (lane >> 4) * 8);

  f32x4 o[4] = {};
  float mrun[4], lrun[4];
#pragma unroll
  for (int r = 0; r < 4; ++r) { mrun[r] = -1e30f; lrun[r] = 0.f; }

  const int iq = qt * 64 + wave * 16 + (lane >> 4) * 4;  // + r gives query row
  const int yi = iq >> 5, xi = iq & 31;

  for (int kt = 0; kt < 16; ++kt) {
    __syncthreads();  // prev iter's PV done reading Ks/Vs
    stage64<2>(kmat + ((size_t)bh * 1024 + kt * 64) * 64, 64, Ks, t);
    stage64<2>(vT + (size_t)bh * 64 * 1024 + kt * 64, 1024, Vs, t);
    __syncthreads();

    // S = Q @ K^T  (scale already folded into q)
    f32x4 s[4] = {};
#pragma unroll
    for (int kk = 0; kk < 2; ++kk) {
#pragma unroll
      for (int n = 0; n < 4; ++n) {
        bf16x8 kf = ldsfrag(Ks, n * 16 + (lane & 15), kk * 4 + (lane >> 4));
        s[n] = MFMA(qf[kk], kf, s[n]);
      }
    }

    // + relative position bias
#pragma unroll
    for (int n = 0; n < 4; ++n) {
      int j = kt * 64 + n * 16 + (lane & 15);
      int dy = yi - (j >> 5) + 31;
      int dx0 = xi - (j & 31) + 31;
      const float* bp = bias_s + dy * 63 + dx0;
#pragma unroll
      for (int r = 0; r < 4; ++r) s[n][r] += bp[r];
    }

    // online softmax (row stats across the 16 lanes of each quarter-wave)
#pragma unroll
    for (int r = 0; r < 4; ++r) {
      float mx = fmaxf(fmaxf(s[0][r], s[1][r]), fmaxf(s[2][r], s[3][r]));
#pragma unroll
      for (int d = 1; d < 16; d <<= 1) mx = fmaxf(mx, __shfl_xor(mx, d));
      float mn = fmaxf(mrun[r], mx);
      float al = __expf(mrun[r] - mn);
      mrun[r] = mn;
      float ps = 0.f;
#pragma unroll
      for (int n = 0; n < 4; ++n) {
        float p = __expf(s[n][r] - mn);
        s[n][r] = p;
        ps += p;
      }
#pragma unroll
      for (int d = 1; d < 16; d <<= 1) ps += __shfl_xor(ps, d);
      lrun[r] = lrun[r] * al + ps;
#pragma unroll
      for (int nd = 0; nd < 4; ++nd) o[nd][r] *= al;
    }

    // P -> LDS bf16 (swizzled); rows are wave-local so no barrier needed
#pragma unroll
    for (int n = 0; n < 4; ++n) {
#pragma unroll
      for (int r = 0; r < 4; ++r) {
        int prow = wave * 16 + (lane >> 4) * 4 + r;
        int byte = prow * 128 + ((n * 16 + (lane & 15)) * 2);
        byte ^= (prow & 7) << 4;
        *(u16*)((char*)Ps + byte) = f2b(s[n][r]);
      }
    }

    // O += P @ V   (Vs holds V^T: rows = d, cols = key)
#pragma unroll
    for (int kk = 0; kk < 2; ++kk) {
      bf16x8 pf = ldsfrag(Ps, wave * 16 + (lane & 15), kk * 4 + (lane >> 4));
#pragma unroll
      for (int nd = 0; nd < 4; ++nd) {
        bf16x8 vf = ldsfrag(Vs, nd * 16 + (lane & 15), kk * 4 + (lane >> 4));
        o[nd] = MFMA(pf, vf, o[nd]);
      }
    }
  }

  // epilogue: O/l -> attn-out (B, N, nh*hd) bf16
#pragma unroll
  for (int nd = 0; nd < 4; ++nd) {
#pragma unroll
    for (int r = 0; r < 4; ++r) {
      int i = iq + r;
      int d = nd * 16 + (lane & 15);
      float val = o[nd][r] / lrun[r];
      ao[((size_t)b * 1024 + i) * 768 + h * 64 + d] = f2b(val);
    }
  }
}

// ---------------------------------------------------------------- launcher
extern "C" void kernel_launch(void* const* d_in, const int* in_sizes, int n_in,
                              void* d_out, int out_size, void* d_ws, size_t ws_size,
                              hipStream_t stream) {
  const float* x = (const float*)d_in[0];
  const float* qkvw = (const float*)d_in[1];
  const float* projw = (const float*)d_in[2];
  const float* projb = (const float*)d_in[3];
  const float* btab = (const float*)d_in[4];
  float* out = (float*)d_out;
  char* ws = (char*)d_ws;

  // workspace layout (bytes)
  u16* xb = (u16*)(ws);                    // 8192*768 bf16 = 12,582,912 B
  u16* wqkvT = (u16*)(ws + 12582912);      // 2304*768 bf16 =  3,538,944 B
  u16* wprojT = (u16*)(ws + 16121856);     //  768*768 bf16 =  1,179,648 B
  u16* qbuf = (u16*)(ws + 17301504);       // 12,582,912 B
  u16* kbuf = (u16*)(ws + 29884416);       // 12,582,912 B
  u16* vTbuf = (u16*)(ws + 42467328);      // 12,582,912 B  (total ~55 MB)
  u16* ao = xb;  // reuse: xb dead after QKV GEMM (stream-serialized)

  cast_x_kernel<<<6144, 256, 0, stream>>>(x, xb, 8192 * 768 / 4);
  transpose_cast<<<dim3(72, 24), 256, 0, stream>>>(qkvw, wqkvT, 768, 2304);
  transpose_cast<<<dim3(24, 24), 256, 0, stream>>>(projw, wprojT, 768, 768);

  gemm128<0><<<dim3(18, 64), 256, 0, stream>>>(xb, wqkvT, 768, qbuf, kbuf,
                                               vTbuf, nullptr, nullptr, 0);

  attn_kernel<<<dim3(16, 12, 8), 256, 0, stream>>>(qbuf, kbuf, vTbuf, btab, ao);

  gemm128<1><<<dim3(6, 64), 256, 0, stream>>>(ao, wprojT, 768, nullptr, nullptr,
                                              nullptr, projb, out, 768);
}